// Round 11
// baseline (310.085 us; speedup 1.0000x reference)
//
#include <hip/hip_runtime.h>
#include <hip/hip_bf16.h>

// Gram matrix: G = X @ X^T, X = [512, 65536] fp32, out = [512, 512] fp32.
// Round 11: r10 symmetric fused kernel + EQUALIZED CRITICAL PATH.
// r10 counters: gemm 99 us, logical 5.2 TB/s, MfmaUtil 8% — not BW-bound,
// not compute-bound. Diag blocks ran 64 iters (KC=2048 @ BK=32) vs upper's
// 32; per-iter time is latency-dominated (constant vs bytes, r1-r10), so
// the 64-iter diag blocks set the 99 us. Fix: diag blocks use BK=64 —
// stage BOTH k-halves per iter (As = k 0..31, Bs = k 32..63, same 32 KB
// fp32/iter as upper), 2x16 MFMAs per iter. Now EVERY block = 32 iters x
// 32 KB. Grid 512 (2/CU), atomics 8.4M floor, upper path identical to r10.
//   - mirror kernel copies upper tiles transposed into lower (1 MB).

typedef short bf16x8 __attribute__((ext_vector_type(8)));   // 8 bf16 = 4 VGPRs
typedef float f32x4  __attribute__((ext_vector_type(4)));   // MFMA acc

#define HW    65536
#define CDIM  512
#define LDSS  40        // r1's stride (conflict counter proved stride-insensitive)

__device__ __forceinline__ short f2bf(float f) {
    __hip_bfloat16 h = __float2bfloat16(f);   // RNE
    short s;
    __builtin_memcpy(&s, &h, sizeof(short));
    return s;
}

__device__ __forceinline__ bf16x8 cvt8(float4 a, float4 b) {
    bf16x8 v;
    v[0] = f2bf(a.x); v[1] = f2bf(a.y); v[2] = f2bf(a.z); v[3] = f2bf(a.w);
    v[4] = f2bf(b.x); v[5] = f2bf(b.y); v[6] = f2bf(b.z); v[7] = f2bf(b.w);
    return v;
}

__global__ __launch_bounds__(256, 2)
void gram_kernel(const float* __restrict__ X, float* __restrict__ out) {
    // decode: p<128  -> diag tile ti=tj=p>>5, chunk=p&31, KC=2048, BK=64 (32 it)
    //         p>=128 -> upper tile o=(p-128)>>6, chunk=(p-128)&63, KC=1024, BK=32
    const int p = blockIdx.x;
    int ti, tj, kbase;
    if (p < 128) {
        ti = tj = p >> 5;
        kbase = (p & 31) * 2048;
    } else {
        const int q = p - 128;
        const int o = q >> 6;
        const int TI[6] = {0, 0, 0, 1, 1, 2};
        const int TJ[6] = {1, 2, 3, 2, 3, 3};
        ti = TI[o]; tj = TJ[o];
        kbase = (q & 63) * 1024;
    }
    const bool diag = (ti == tj);

    __shared__ short As[128 * LDSS];    // diag: k-half 0 | upper: A panel
    __shared__ short Bs[128 * LDSS];    // diag: k-half 1 | upper: B panel

    const int t    = threadIdx.x;
    const int wave = t >> 6;
    const int lane = t & 63;
    const int wm   = wave & 1;          // 2x2 wave grid, each wave = 64x64
    const int wn   = wave >> 1;

    // --- staging mapping (r1's): 2 threads per row, 16 consecutive fp32 ---
    const int srow  = t >> 1;           // 0..127
    const int shalf = (t & 1) * 16;     // k offset 0 or 16
    const float* pa = X + (size_t)(ti * 128 + srow) * HW + kbase + shalf;
    const float* pb = X + (size_t)(tj * 128 + srow) * HW + kbase + shalf;
    short* wa = As + srow * LDSS + shalf;
    short* wb = Bs + srow * LDSS + shalf;

    // --- fragment read offsets (A-operand: m = lane&15, k-group = lane>>4) ---
    const int fm = lane & 15;
    const int kg = lane >> 4;           // 0..3, each group = 8 contiguous k
    int a_off[4], b_off[4];
#pragma unroll
    for (int i = 0; i < 4; ++i) {
        a_off[i] = (wm * 64 + i * 16 + fm) * LDSS + kg * 8;
        b_off[i] = (wn * 64 + i * 16 + fm) * LDSS + kg * 8;
    }

    f32x4 acc[4][4];
#pragma unroll
    for (int i = 0; i < 4; ++i)
#pragma unroll
        for (int j = 0; j < 4; ++j)
            acc[i][j] = (f32x4){0.f, 0.f, 0.f, 0.f};

    for (int it = 0; it < 32; ++it) {
        // global fp32 loads: 32 floats/thread either way.
        // diag: cols [shalf, shalf+16) and [shalf+32, shalf+48) of ONE panel
        // upper: cols [shalf, shalf+16) of TWO panels
        float4 a0 = *(const float4*)(pa + 0);
        float4 a1 = *(const float4*)(pa + 4);
        float4 a2 = *(const float4*)(pa + 8);
        float4 a3 = *(const float4*)(pa + 12);
        float4 b0, b1, b2, b3;
        if (diag) {
            b0 = *(const float4*)(pa + 32);
            b1 = *(const float4*)(pa + 36);
            b2 = *(const float4*)(pa + 40);
            b3 = *(const float4*)(pa + 44);
        } else {
            b0 = *(const float4*)(pb + 0);
            b1 = *(const float4*)(pb + 4);
            b2 = *(const float4*)(pb + 8);
            b3 = *(const float4*)(pb + 12);
        }

        bf16x8 va0 = cvt8(a0, a1), va1 = cvt8(a2, a3);
        bf16x8 vb0 = cvt8(b0, b1), vb1 = cvt8(b2, b3);

        __syncthreads();   // prior iteration's LDS reads complete
        *(bf16x8*)(wa + 0) = va0;
        *(bf16x8*)(wa + 8) = va1;
        *(bf16x8*)(wb + 0) = vb0;    // diag: k-half 1 | upper: B panel
        *(bf16x8*)(wb + 8) = vb1;
        __syncthreads();   // stage visible to all waves

        if (diag) {
            // two k-steps, both frags from the same (only) panel
#pragma unroll
            for (int h = 0; h < 2; ++h) {
                const short* buf = h ? Bs : As;
                bf16x8 af[4], bfr[4];
#pragma unroll
                for (int i = 0; i < 4; ++i) af[i]  = *(const bf16x8*)(buf + a_off[i]);
#pragma unroll
                for (int j = 0; j < 4; ++j) bfr[j] = *(const bf16x8*)(buf + b_off[j]);
#pragma unroll
                for (int i = 0; i < 4; ++i)
#pragma unroll
                    for (int j = 0; j < 4; ++j)
                        acc[i][j] = __builtin_amdgcn_mfma_f32_16x16x32_bf16(
                            af[i], bfr[j], acc[i][j], 0, 0, 0);
            }
            pa += 64;
        } else {
            bf16x8 af[4], bfr[4];
#pragma unroll
            for (int i = 0; i < 4; ++i) af[i]  = *(const bf16x8*)(As + a_off[i]);
#pragma unroll
            for (int j = 0; j < 4; ++j) bfr[j] = *(const bf16x8*)(Bs + b_off[j]);
#pragma unroll
            for (int i = 0; i < 4; ++i)
#pragma unroll
                for (int j = 0; j < 4; ++j)
                    acc[i][j] = __builtin_amdgcn_mfma_f32_16x16x32_bf16(
                        af[i], bfr[j], acc[i][j], 0, 0, 0);
            pa += 32;
            pb += 32;
        }
    }

    // --- epilogue: row-major coalesced atomics (diag/upper tiles only) ---
    // C/D layout (verified m89/m91): col = lane&15, row = (lane>>4)*4 + reg
    const int orow0 = ti * 128 + wm * 64 + (lane >> 4) * 4;
    const int ocol0 = tj * 128 + wn * 64 + fm;
#pragma unroll
    for (int i = 0; i < 4; ++i)
#pragma unroll
        for (int j = 0; j < 4; ++j)
#pragma unroll
            for (int r = 0; r < 4; ++r)
                atomicAdd(out + (orow0 + i * 16 + r) * CDIM + ocol0 + j * 16,
                          acc[i][j][r]);
}

// ---------------- mirror: copy upper tiles transposed into lower ----------------
__global__ __launch_bounds__(256)
void mirror_kernel(float* __restrict__ out) {
    const int id = blockIdx.x * 256 + threadIdx.x;   // 0..262143
    const int r = id >> 9;
    const int c = id & 511;
    if ((r >> 7) > (c >> 7))
        out[id] = out[c * CDIM + r];
}

extern "C" void kernel_launch(void* const* d_in, const int* in_sizes, int n_in,
                              void* d_out, int out_size, void* d_ws, size_t ws_size,
                              hipStream_t stream) {
    const float* x = (const float*)d_in[0];
    float* out = (float*)d_out;

    // zero the accumulator (harness poisons d_out with 0xAA before every launch)
    hipMemsetAsync(d_out, 0, (size_t)out_size * sizeof(float), stream);

    gram_kernel<<<dim3(512), dim3(256), 0, stream>>>(x, out);
    mirror_kernel<<<dim3(1024), dim3(256), 0, stream>>>(out);
}